// Round 1
// baseline (830.627 us; speedup 1.0000x reference)
//
#include <hip/hip_runtime.h>

#define T_ 2048
#define D_ 4096
#define H_ 32
#define G_ 8
#define HD_ 128

typedef float f32x4 __attribute__((ext_vector_type(4)));
typedef __bf16 bf16x8 __attribute__((ext_vector_type(8)));
typedef unsigned short u16x8 __attribute__((ext_vector_type(8)));

__device__ __forceinline__ unsigned short f2bf(float f) {
  unsigned u = __builtin_bit_cast(unsigned, f);
  u += 0x7FFFu + ((u >> 16) & 1u);
  return (unsigned short)(u >> 16);
}
__device__ __forceinline__ float bf2f(unsigned short h) {
  return __builtin_bit_cast(float, (unsigned)h << 16);
}

__device__ __forceinline__ void gload_lds16(const unsigned short* g, unsigned short* l) {
  __builtin_amdgcn_global_load_lds((const __attribute__((address_space(1))) void*)g,
                                   (__attribute__((address_space(3))) void*)l, 16, 0, 0);
}

// ---------------- elementwise f32 -> bf16 ----------------
__global__ __launch_bounds__(256) void convert_bf16(const float* __restrict__ in,
                                                    unsigned short* __restrict__ out) {
  const size_t i = ((size_t)blockIdx.x * 256 + threadIdx.x) * 8;
  float4 a = *(const float4*)(in + i);
  float4 b = *(const float4*)(in + i + 4);
  u16x8 o;
  o[0] = f2bf(a.x); o[1] = f2bf(a.y); o[2] = f2bf(a.z); o[3] = f2bf(a.w);
  o[4] = f2bf(b.x); o[5] = f2bf(b.y); o[6] = f2bf(b.z); o[7] = f2bf(b.w);
  *(u16x8*)(out + i) = o;
}

// ---------------- tiled transpose + convert: W (R,C) f32 -> Wt (C,R) bf16 ----------------
__global__ __launch_bounds__(256) void transpose_convert(const float* __restrict__ Wm,
                                                         unsigned short* __restrict__ Wt,
                                                         int R, int C) {
  __shared__ float tile[64][65];
  const int r0 = blockIdx.x * 64, c0 = blockIdx.y * 64;
  const int lr4 = threadIdx.x >> 6, lc = threadIdx.x & 63;
#pragma unroll
  for (int i = 0; i < 16; ++i) {
    int r = i * 4 + lr4;
    tile[r][lc] = Wm[(size_t)(r0 + r) * C + c0 + lc];
  }
  __syncthreads();
#pragma unroll
  for (int i = 0; i < 16; ++i) {
    int r = i * 4 + lr4;
    Wt[(size_t)(c0 + r) * R + r0 + lc] = f2bf(tile[lc][r]);
  }
}

// ---------------- transpose v: (T, G*HD) bf16 -> (G, HD, T) bf16 ----------------
__global__ __launch_bounds__(256) void transpose_v(const unsigned short* __restrict__ v,
                                                   unsigned short* __restrict__ vt) {
  __shared__ unsigned short tile[64][65];
  const int t0 = blockIdx.x * 64, d0 = blockIdx.y * 64, g = blockIdx.z;
  const int lr4 = threadIdx.x >> 6, lc = threadIdx.x & 63;
#pragma unroll
  for (int i = 0; i < 16; ++i) {
    int r = i * 4 + lr4;
    tile[r][lc] = v[(size_t)(t0 + r) * (G_ * HD_) + g * HD_ + d0 + lc];
  }
  __syncthreads();
#pragma unroll
  for (int i = 0; i < 16; ++i) {
    int r = i * 4 + lr4;
    vt[((size_t)g * HD_ + d0 + r) * T_ + t0 + lc] = tile[lc][r];
  }
}

// ---------------- RMSNorm + RoPE; (T, NH*HD) bf16 -> (NH, T, HD) bf16 ----------------
__global__ __launch_bounds__(256) void norm_rope(const unsigned short* __restrict__ raw,
                                                 unsigned short* __restrict__ outp,
                                                 const float* __restrict__ w,
                                                 const float* __restrict__ cs,
                                                 const float* __restrict__ sn, int NH) {
  const int row = blockIdx.x * 4 + (threadIdx.x >> 6);
  const int lane = threadIdx.x & 63;
  const int t = row / NH, h = row - t * NH;
  const unsigned short* src = raw + (size_t)row * HD_;
  float u1 = bf2f(src[lane]);
  float u2 = bf2f(src[lane + 64]);
  float ss = u1 * u1 + u2 * u2;
#pragma unroll
  for (int m = 1; m < 64; m <<= 1) ss += __shfl_xor(ss, m);
  float rr = rsqrtf(ss * (1.f / 128.f) + 1e-6f);
  float c = cs[(size_t)t * HD_ + lane];  // cos[d] == cos[d+64] (concat(freqs,freqs))
  float s = sn[(size_t)t * HD_ + lane];
  float a = u1 * rr * w[lane];
  float b = u2 * rr * w[lane + 64];
  unsigned short* dst = outp + ((size_t)h * T_ + t) * HD_;
  dst[lane]      = f2bf(a * c - b * s);
  dst[lane + 64] = f2bf(b * c + a * s);
}

// ---------------- m97-style GEMM: C(M,N) = A(M,K)bf16 * Bt(N,K)bf16 ----------------
template <int OUTF32>
__global__ __launch_bounds__(256) void gemm_bt(const unsigned short* __restrict__ A,
                                               const unsigned short* __restrict__ Bt,
                                               void* __restrict__ Cv, int M, int N, int K) {
  __shared__ __align__(16) unsigned short As[128 * 32];
  __shared__ __align__(16) unsigned short Bs[128 * 32];
  const int tid = threadIdx.x;
  const int wid = tid >> 6, lane = tid & 63;
  const int lr = lane & 15, lhi = lane >> 4;
  const int brow = blockIdx.x * 128, bcol = blockIdx.y * 128;
  const int wr = wid >> 1, wc = wid & 1;
  f32x4 acc[4][4];
#pragma unroll
  for (int m = 0; m < 4; ++m)
#pragma unroll
    for (int n = 0; n < 4; ++n) acc[m][n] = (f32x4){0.f, 0.f, 0.f, 0.f};

  const int srow = wid * 16 + (lane >> 2);
  const int scol = (lane & 3) * 8;
  const unsigned short* ga = A + (size_t)(brow + srow) * K + scol;
  const unsigned short* gb = Bt + (size_t)(bcol + srow) * K + scol;
  unsigned short* la = &As[wid * 512];
  unsigned short* lb = &Bs[wid * 512];

  for (int kt = 0; kt < K; kt += 32) {
    gload_lds16(ga + kt, la);
    gload_lds16(ga + (size_t)64 * K + kt, la + 2048);
    gload_lds16(gb + kt, lb);
    gload_lds16(gb + (size_t)64 * K + kt, lb + 2048);
    __syncthreads();
    bf16x8 af[4], bv[4];
#pragma unroll
    for (int m = 0; m < 4; ++m) af[m] = *(const bf16x8*)&As[(wr * 64 + m * 16 + lr) * 32 + lhi * 8];
#pragma unroll
    for (int n = 0; n < 4; ++n) bv[n] = *(const bf16x8*)&Bs[(wc * 64 + n * 16 + lr) * 32 + lhi * 8];
#pragma unroll
    for (int m = 0; m < 4; ++m)
#pragma unroll
      for (int n = 0; n < 4; ++n)
        acc[m][n] = __builtin_amdgcn_mfma_f32_16x16x32_bf16(af[m], bv[n], acc[m][n], 0, 0, 0);
    __syncthreads();
  }
#pragma unroll
  for (int m = 0; m < 4; ++m)
#pragma unroll
    for (int n = 0; n < 4; ++n) {
      int col = bcol + wc * 64 + n * 16 + lr;
#pragma unroll
      for (int r = 0; r < 4; ++r) {
        int row = brow + wr * 64 + m * 16 + lhi * 4 + r;
        if (OUTF32)
          ((float*)Cv)[(size_t)row * N + col] = acc[m][n][r];
        else
          ((unsigned short*)Cv)[(size_t)row * N + col] = f2bf(acc[m][n][r]);
      }
    }
}

// ---------------- causal flash attention: 1 wave per 16 q-rows per head ----------------
__global__ __launch_bounds__(64) void flash_attn(const unsigned short* __restrict__ q,
                                                 const unsigned short* __restrict__ k,
                                                 const unsigned short* __restrict__ vt,
                                                 unsigned short* __restrict__ attnb) {
  const int h = blockIdx.y;
  const int g = h >> 2;  // GS = 4
  const int q0 = blockIdx.x * 16;
  const int lane = threadIdx.x;
  const int lr = lane & 15, lhi = lane >> 4;
  __shared__ __align__(16) unsigned short p_lds[16 * 32];

  bf16x8 qf[4];
  {
    const unsigned short* qrow = q + ((size_t)h * T_ + q0 + lr) * HD_ + lhi * 8;
#pragma unroll
    for (int c = 0; c < 4; ++c) qf[c] = *(const bf16x8*)(qrow + c * 32);
  }
  f32x4 accO[8];
#pragma unroll
  for (int i = 0; i < 8; ++i) accO[i] = (f32x4){0.f, 0.f, 0.f, 0.f};
  float mrow[4] = {-1e30f, -1e30f, -1e30f, -1e30f};
  float lrow[4] = {0.f, 0.f, 0.f, 0.f};

  const int nkv = (q0 >> 5) + 1;
  for (int kt = 0; kt < nkv; ++kt) {
    const int kv0 = kt << 5;
    f32x4 s0 = (f32x4){0.f, 0.f, 0.f, 0.f}, s1 = (f32x4){0.f, 0.f, 0.f, 0.f};
    const unsigned short* kr0 = k + ((size_t)g * T_ + kv0 + lr) * HD_ + lhi * 8;
    const unsigned short* kr1 = kr0 + 16 * HD_;
#pragma unroll
    for (int c = 0; c < 4; ++c) {
      s0 = __builtin_amdgcn_mfma_f32_16x16x32_bf16(qf[c], *(const bf16x8*)(kr0 + c * 32), s0, 0, 0, 0);
      s1 = __builtin_amdgcn_mfma_f32_16x16x32_bf16(qf[c], *(const bf16x8*)(kr1 + c * 32), s1, 0, 0, 0);
    }
    const float scale = 0.08838834764831845f;  // 1/sqrt(128)
    float pm[4];
#pragma unroll
    for (int r = 0; r < 4; ++r) {
      int row = q0 + lhi * 4 + r;
      float v0 = (kv0 + lr <= row) ? s0[r] * scale : -1e30f;
      float v1 = (kv0 + 16 + lr <= row) ? s1[r] * scale : -1e30f;
      s0[r] = v0; s1[r] = v1;
      pm[r] = fmaxf(v0, v1);
    }
#pragma unroll
    for (int m = 1; m < 16; m <<= 1)
#pragma unroll
      for (int r = 0; r < 4; ++r) pm[r] = fmaxf(pm[r], __shfl_xor(pm[r], m));
    float alpha[4], psum[4];
#pragma unroll
    for (int r = 0; r < 4; ++r) {
      float mnew = fmaxf(mrow[r], pm[r]);
      alpha[r] = __expf(mrow[r] - mnew);
      mrow[r] = mnew;
      float p0 = __expf(s0[r] - mnew);
      float p1 = __expf(s1[r] - mnew);
      s0[r] = p0; s1[r] = p1;
      psum[r] = p0 + p1;
    }
#pragma unroll
    for (int m = 1; m < 16; m <<= 1)
#pragma unroll
      for (int r = 0; r < 4; ++r) psum[r] += __shfl_xor(psum[r], m);
#pragma unroll
    for (int r = 0; r < 4; ++r) lrow[r] = lrow[r] * alpha[r] + psum[r];
#pragma unroll
    for (int dt = 0; dt < 8; ++dt)
#pragma unroll
      for (int r = 0; r < 4; ++r) accO[dt][r] *= alpha[r];
#pragma unroll
    for (int r = 0; r < 4; ++r) {
      p_lds[(lhi * 4 + r) * 32 + lr] = f2bf(s0[r]);
      p_lds[(lhi * 4 + r) * 32 + 16 + lr] = f2bf(s1[r]);
    }
    __syncthreads();
    bf16x8 pa = *(const bf16x8*)&p_lds[lr * 32 + lhi * 8];
    const unsigned short* vbase = vt + ((size_t)g * HD_ + lr) * T_ + kv0 + lhi * 8;
#pragma unroll
    for (int dt = 0; dt < 8; ++dt)
      accO[dt] = __builtin_amdgcn_mfma_f32_16x16x32_bf16(
          pa, *(const bf16x8*)(vbase + (size_t)dt * 16 * T_), accO[dt], 0, 0, 0);
    __syncthreads();
  }
#pragma unroll
  for (int r = 0; r < 4; ++r) {
    float inv = 1.f / lrow[r];
    size_t rowoff = (size_t)(q0 + lhi * 4 + r) * (H_ * HD_) + h * HD_;
#pragma unroll
    for (int dt = 0; dt < 8; ++dt) attnb[rowoff + dt * 16 + lr] = f2bf(accO[dt][r] * inv);
  }
}

extern "C" void kernel_launch(void* const* d_in, const int* in_sizes, int n_in,
                              void* d_out, int out_size, void* d_ws, size_t ws_size,
                              hipStream_t stream) {
  const float* x = (const float*)d_in[0];
  // d_in[1] = mask (bool) — causal mask computed analytically, unused
  const float* cosT = (const float*)d_in[2];
  const float* sinT = (const float*)d_in[3];
  const float* Wq = (const float*)d_in[4];
  const float* Wk = (const float*)d_in[5];
  const float* Wv = (const float*)d_in[6];
  const float* Wo = (const float*)d_in[7];
  const float* qn = (const float*)d_in[8];
  const float* kn = (const float*)d_in[9];

  unsigned char* w = (unsigned char*)d_ws;
  unsigned short* xb    = (unsigned short*)(w);              // 16 MB (T,D) bf16
  unsigned short* WqT   = (unsigned short*)(w + 16777216);   // 32 MB (4096,4096)
  unsigned short* WkT   = (unsigned short*)(w + 50331648);   // 8 MB (1024,4096)
  unsigned short* WvT   = (unsigned short*)(w + 58720256);   // 8 MB
  unsigned short* qrawb = (unsigned short*)(w + 67108864);   // 16 MB (T, H*HD)
  unsigned short* krawb = (unsigned short*)(w + 83886080);   // 4 MB (T, G*HD)
  unsigned short* vrawb = (unsigned short*)(w + 88080384);   // 4 MB
  unsigned short* qbuf  = (unsigned short*)(w + 92274688);   // 16 MB (H,T,HD)
  unsigned short* kbuf  = (unsigned short*)(w + 109051904);  // 4 MB (G,T,HD)
  unsigned short* vtb   = (unsigned short*)(w + 113246208);  // 4 MB (G,HD,T)  -> total 117.4 MB
  unsigned short* WoT   = WqT;  // alias: Wq tile dead after QKV GEMMs
  unsigned short* attnb = xb;   // alias: x dead after QKV GEMMs

  convert_bf16<<<dim3(4096), dim3(256), 0, stream>>>(x, xb);
  transpose_convert<<<dim3(64, 64), dim3(256), 0, stream>>>(Wq, WqT, 4096, 4096);
  transpose_convert<<<dim3(64, 16), dim3(256), 0, stream>>>(Wk, WkT, 4096, 1024);
  transpose_convert<<<dim3(64, 16), dim3(256), 0, stream>>>(Wv, WvT, 4096, 1024);

  gemm_bt<0><<<dim3(16, 32), dim3(256), 0, stream>>>(xb, WqT, (void*)qrawb, 2048, 4096, 4096);
  gemm_bt<0><<<dim3(16, 8), dim3(256), 0, stream>>>(xb, WkT, (void*)krawb, 2048, 1024, 4096);
  gemm_bt<0><<<dim3(16, 8), dim3(256), 0, stream>>>(xb, WvT, (void*)vrawb, 2048, 1024, 4096);

  norm_rope<<<dim3(16384), dim3(256), 0, stream>>>(qrawb, qbuf, qn, cosT, sinT, H_);
  norm_rope<<<dim3(4096), dim3(256), 0, stream>>>(krawb, kbuf, kn, cosT, sinT, G_);
  transpose_v<<<dim3(32, 2, 8), dim3(256), 0, stream>>>(vrawb, vtb);
  transpose_convert<<<dim3(64, 64), dim3(256), 0, stream>>>(Wo, WoT, 4096, 4096);

  flash_attn<<<dim3(128, 32), dim3(64), 0, stream>>>(qbuf, kbuf, vtb, attnb);

  gemm_bt<1><<<dim3(16, 32), dim3(256), 0, stream>>>(attnb, WoT, d_out, 2048, 4096, 4096);
}